// Round 8
// baseline (160.063 us; speedup 1.0000x reference)
//
#include <hip/hip_runtime.h>
#include <stdint.h>
#include <math.h>

typedef unsigned long long u64;

// Problem-size caps (H=W=48 grid per reference).
#define NMAXC 2304
#define EMAXC 6721
#define FMAXC 4418
#define KRANGES 128
#define CMAX 64
#define GRID 256
#define BLK 1024
#define TSZ 512

// Monotone float -> uint32 mapping (IEEE total order for non-NaN).
static __device__ __forceinline__ uint32_t f2ord(float f) {
  uint32_t u = __float_as_uint(f);
  return (u & 0x80000000u) ? ~u : (u | 0x80000000u);
}

// ECL-CC representative with inline path compression.
static __device__ __forceinline__ int rep(volatile int* par, int v) {
  int p = par[v];
  if (p == v) return v;
  int gp = par[p];
  while (p != gp) {
    par[v] = gp;
    v = p; p = gp; gp = par[p];
  }
  return p;
}

// Device-scope grid barrier: all GRID blocks are co-resident (1 block/CU).
static __device__ __forceinline__ void gbar(int* cnt) {
  __syncthreads();
  if (threadIdx.x == 0) {
    __threadfence();
    atomicAdd(cnt, 1);
    while (__hip_atomic_load(cnt, __ATOMIC_ACQUIRE, __HIP_MEMORY_SCOPE_AGENT) < GRID)
      __builtin_amdgcn_s_sleep(1);
    __threadfence();
  }
  __syncthreads();
}

__global__ __launch_bounds__(BLK) void k_mega(
    const float* img, const int* edges, const int* tri_edges, int* gb,
    float* vals, u64* keys, uint32_t* pack, int* adj,
    int* vr_to_rank, int* er_to_rank, int* noderank1,
    uint32_t* eAB0, uint32_t* eAB1, float* vsorted, float* out,
    int N, int E, int F, int m, int W, int C, int out_n) {
  __shared__ __align__(16) u64 s_tile[TSZ];
  __shared__ int s_par[FMAXC + 1];
  __shared__ uint32_t s_rr[CMAX];
  __shared__ int s_ci[CMAX];
  __shared__ int2 s_pairs[CMAX];
  __shared__ int s_cnt;
  int tid = threadIdx.x, bid = blockIdx.x;
  int gi = bid * BLK + tid;
  int FH = F >> 1;

  // ---- Phase 0: prep (zero out+pack, values, keys, structural adjacency) ----
  {
    int PM = out_n > m ? out_n : m;
    int F3 = 3 * F;
    if (F3 > PM) PM = F3;
    for (int i = gi; i < PM; i += GRID * BLK) {
      if (i < out_n) out[i] = 0.0f;
      if (i < m) {
        pack[i] = 0u;
        float v;
        if (i < N) {
          v = img[i];
        } else if (i < N + E) {
          int e = i - N;
          v = fmaxf(img[edges[2 * e]], img[edges[2 * e + 1]]);
        } else {
          int t = i - N - E;
          float mx = -3.402823466e38f;
          #pragma unroll
          for (int k = 0; k < 3; ++k) {
            int e = tri_edges[3 * t + k];
            mx = fmaxf(mx, fmaxf(img[edges[2 * e]], img[edges[2 * e + 1]]));
          }
          v = mx;
        }
        vals[i] = v;
        keys[i] = ((u64)f2ord(v) << 32) | (u64)(uint32_t)i;
      }
      if (i < F3) {
        // Reference complex: t < F/2 (A-half) and t >= F/2 (B-half); every edge
        // touches at most one triangle of each half -> race-free plain stores.
        int e = tri_edges[i];
        int t = i / 3;
        adj[2 * e + (t >= FH ? 1 : 0)] = t;
      }
    }
  }
  gbar(gb + 0);

  // ---- Phase 1: counting-rank (tile x key-block cells, grid-strided) ----
  {
    int NTt = (m + TSZ - 1) / TSZ;
    int KBt = (m + BLK - 1) / BLK;
    int ncell = NTt * KBt;
    for (int cell = bid; cell < ncell; cell += GRID) {
      int tIdx = cell % NTt, kb = cell / NTt;
      int base = tIdx * TSZ;
      int lim = min(TSZ, m - base);
      __syncthreads();
      if (tid < TSZ) s_tile[tid] = (tid < lim) ? keys[base + tid] : ~0ull;
      __syncthreads();
      int ki = kb * BLK + tid;
      u64 k0 = (ki < m) ? keys[ki] : ~0ull;
      int cls0 = (ki < N) ? 0 : (ki < N + E ? 1 : 2);
      int sb1 = min(max(N - base, 0), lim);
      int sb2 = min(max(N + E - base, 0), lim);
      int segb[4] = {0, sb1, sb2, lim};
      int tot = 0, cc = 0;
      #pragma unroll
      for (int sg = 0; sg < 3; ++sg) {
        int lo = segb[sg], hh = segb[sg + 1], t = 0, j = lo;
        if (j < hh && (j & 1)) { t += (s_tile[j] < k0); ++j; }
        #pragma unroll 4
        for (; j + 1 < hh; j += 2) {
          t += (s_tile[j] < k0) + (s_tile[j + 1] < k0);
        }
        if (j < hh) t += (s_tile[j] < k0);
        tot += t;
        if (cls0 == sg) cc += t;
      }
      if (ki < m) atomicAdd(&pack[ki], ((uint32_t)cc << 16) | (uint32_t)tot);
    }
  }
  gbar(gb + 1);

  // ---- Phase 2: maps (scatter + relabeled edge lists, geometric boundary) ----
  for (int i = gi; i < m; i += GRID * BLK) {
    uint32_t pk = pack[i];
    int rank = (int)(pk & 0xffffu);
    int cls = (int)(pk >> 16);
    vsorted[rank] = vals[i];
    if (i < N) {
      vr_to_rank[cls] = rank;
    } else if (i < N + E) {
      int e = i - N, er = cls;
      er_to_rank[er] = rank;
      int a = edges[2 * e], b = edges[2 * e + 1];
      uint32_t va = pack[a] >> 16, vb = pack[b] >> 16;
      eAB0[er] = (va << 16) | vb;
      int ra = a / W, ca = a - ra * W, rb = b / W, cb = b - rb * W;
      bool he = (ra == rb), ve = (ca == cb);
      bool v0 = !((he && ra == W - 1) || (ve && ca == W - 1));  // A-half present?
      bool v1 = !((he && ra == 0) || (ve && ca == 0));          // B-half present?
      uint32_t na = v0 ? ((uint32_t)F - (pack[N + E + adj[2 * e]] >> 16)) : 0u;
      uint32_t nb = v1 ? ((uint32_t)F - (pack[N + E + adj[2 * e + 1]] >> 16)) : 0u;
      eAB1[E - 1 - er] = (na << 16) | nb;
    } else {
      noderank1[F - cls] = rank;  // dual node id = F - trank (outer = 0)
    }
  }
  gbar(gb + 2);

  // ---- Phase 3: range-parallel elder-rule pairing + emit ----
  {
    volatile int* vp = s_par;
    int g = bid / KRANGES;
    int r = bid % KRANGES;
    int NODES = (g == 0) ? N : (F + 1);
    const uint32_t* eAB = (g == 0) ? eAB0 : eAB1;
    int P = r * C;
    if (P >= E) return;
    int hi = min(P + C, E);
    int nR = hi - P;
    for (int x = tid; x < NODES; x += BLK) s_par[x] = x;
    __syncthreads();
    // Phase A: async hooking over prefix edges [0, P), dual-chain walks
    for (int i = tid; i < P; i += BLK) {
      uint32_t ab = eAB[i];
      int va = (int)(ab >> 16), vb = (int)(ab & 0xffffu);
      int pa = vp[va], pb = vp[vb];
      int ga = vp[pa], gb2 = vp[pb];
      while (pa != ga || pb != gb2) {
        if (pa != ga) { vp[va] = ga; va = pa; pa = ga; ga = vp[pa]; }
        if (pb != gb2) { vp[vb] = gb2; vb = pb; pb = gb2; gb2 = vp[pb]; }
      }
      int u = pa, w = pb;
      while (u != w) {
        if (u < w) { int t = u; u = w; w = t; }
        int old = atomicCAS((int*)&s_par[u], u, w);
        if (old == u) break;
        u = rep(vp, old);
        w = rep(vp, w);
      }
    }
    __syncthreads();
    // Full compression: par[x] = root(x) (= component min)
    for (int x = tid; x < NODES; x += BLK) {
      int r0 = x;
      while (vp[r0] != r0) r0 = vp[r0];
      s_par[x] = r0;
    }
    __syncthreads();
    // Pre-resolve range-edge roots
    for (int q = tid; q < nR; q += BLK) {
      uint32_t ab = eAB[P + q];
      int ra = s_par[ab >> 16];
      int rb = s_par[ab & 0xffffu];
      s_rr[q] = ((uint32_t)ra << 16) | (uint32_t)rb;
    }
    __syncthreads();
    // Wave-0: compact candidates (roots differ), then lane-0 serial UF
    if (tid < 64) {
      uint32_t rr = (tid < nR) ? s_rr[tid] : 0u;
      int keep = (tid < nR) && ((rr >> 16) != (rr & 0xffffu));
      u64 mask = __ballot(keep);
      if (keep) {
        int idx = __popcll(mask & ((1ull << tid) - 1ull));
        s_rr[idx] = rr;
        s_ci[idx] = tid;
      }
      int kc = __popcll(mask);
      if (tid == 0) {
        int c = 0;
        for (int i = 0; i < kc; ++i) {
          uint32_t rr2 = s_rr[i];
          int x = (int)(rr2 >> 16), y = (int)(rr2 & 0xffffu);
          while (s_par[x] != x) { s_par[x] = s_par[s_par[x]]; x = s_par[x]; }
          while (s_par[y] != y) { s_par[y] = s_par[s_par[y]]; y = s_par[y]; }
          if (x != y) {
            int die = x > y ? x : y, sur = x < y ? x : y;
            s_par[die] = sur;
            s_pairs[c++] = make_int2(die, P + s_ci[i]);
          }
        }
        s_cnt = c;
      }
    }
    __syncthreads();
    // Emit
    int c = s_cnt;
    if (g == 0) {
      for (int q = tid; q < c; q += BLK) {
        int2 pq = s_pairs[q];
        int b = vr_to_rank[pq.x], d = er_to_rank[pq.y];
        out[2 * b] = vsorted[b];
        out[2 * b + 1] = vsorted[d];
      }
      if (r == 0 && tid == 0) {
        // essential dim-0 class: rank 0 birth, death = fmax (rank m-1)
        out[0] = vsorted[0];
        out[1] = vsorted[m - 1];
      }
    } else {
      float* o1 = out + 2 * (size_t)m;
      for (int q = tid; q < c; q += BLK) {
        int2 pq = s_pairs[q];
        int er = E - 1 - pq.y;
        int b = er_to_rank[er], d = noderank1[pq.x];
        o1[2 * b] = vsorted[b];
        o1[2 * b + 1] = vsorted[d];
      }
    }
  }
}

extern "C" void kernel_launch(void* const* d_in, const int* in_sizes, int n_in,
                              void* d_out, int out_size, void* d_ws, size_t ws_size,
                              hipStream_t stream) {
  const float* img = (const float*)d_in[0];
  const int* edges = (const int*)d_in[1];
  const int* tri_edges = (const int*)d_in[2];
  int N = in_sizes[0];
  int E = in_sizes[1] / 2;
  int F = in_sizes[2] / 3;
  int m = N + E + F;
  int C = (E + KRANGES - 1) / KRANGES;
  int W = (int)(sqrt((double)N) + 0.5);
  float* out = (float*)d_out;

  char* p = (char*)d_ws;
  auto alloc = [&](size_t bytes) { char* r = p; p += (bytes + 255) & ~(size_t)255; return r; };
  int* gb          = (int*)alloc(3 * 4);
  u64* keys        = (u64*)alloc((size_t)m * 8);
  float* vals      = (float*)alloc((size_t)m * 4);
  float* vsorted   = (float*)alloc((size_t)m * 4);
  uint32_t* pack   = (uint32_t*)alloc((size_t)m * 4);
  int* vr_to_rank  = (int*)alloc((size_t)N * 4);
  int* er_to_rank  = (int*)alloc((size_t)E * 4);
  int* noderank1   = (int*)alloc((size_t)(F + 1) * 4);
  int* adj         = (int*)alloc((size_t)E * 8);
  uint32_t* eAB0   = (uint32_t*)alloc((size_t)E * 4);
  uint32_t* eAB1   = (uint32_t*)alloc((size_t)E * 4);
  (void)ws_size; (void)n_in;

  hipMemsetAsync(gb, 0, 3 * 4, stream);
  k_mega<<<GRID, BLK, 0, stream>>>(img, edges, tri_edges, gb,
                                   vals, keys, pack, adj,
                                   vr_to_rank, er_to_rank, noderank1,
                                   eAB0, eAB1, vsorted, out,
                                   N, E, F, m, W, C, out_size);
}

// Round 9
// 147.745 us; speedup vs baseline: 1.0834x; 1.0834x over previous
//
#include <hip/hip_runtime.h>
#include <stdint.h>
#include <math.h>

typedef unsigned long long u64;

// Problem-size caps (H=W=48 grid per reference).
#define FMAXC 4418
#define KRANGES 128
#define GRID 256
#define BLK 1024
#define TSZ 1024
#define NLEAF 32
#define LSTR 64   // ints per barrier cacheline slot

// Monotone float -> uint32 mapping (IEEE total order for non-NaN).
static __device__ __forceinline__ uint32_t f2ord(float f) {
  uint32_t u = __float_as_uint(f);
  return (u & 0x80000000u) ? ~u : (u | 0x80000000u);
}

// ECL-CC representative with inline path compression.
static __device__ __forceinline__ int rep(volatile int* par, int v) {
  int p = par[v];
  if (p == v) return v;
  int gp = par[p];
  while (p != gp) {
    par[v] = gp;
    v = p; p = gp; gp = par[p];
  }
  return p;
}

// Async min-hook of one edge into a DSU (dual-chain walks + CAS).
static __device__ __forceinline__ void hook(volatile int* vp, uint32_t ab) {
  int va = (int)(ab >> 16), vb = (int)(ab & 0xffffu);
  int pa = vp[va], pb = vp[vb];
  int ga = vp[pa], gb = vp[pb];
  while (pa != ga || pb != gb) {
    if (pa != ga) { vp[va] = ga; va = pa; pa = ga; ga = vp[pa]; }
    if (pb != gb) { vp[vb] = gb; vb = pb; pb = gb; gb = vp[pb]; }
  }
  int u = pa, w = pb;
  while (u != w) {
    if (u < w) { int t = u; u = w; w = t; }
    int old = atomicCAS((int*)&vp[u], u, w);
    if (old == u) break;
    u = rep(vp, old);
    w = rep(vp, w);
  }
}

// Two-level grid barrier: 32 padded leaf counters -> root -> generation flag.
// Counters are never reset during the kernel (generation-scaled targets);
// k_prep zeroes the block each launch.
static __device__ __forceinline__ void gbar(int* bar, int gen) {
  __syncthreads();
  if (threadIdx.x == 0) {
    __threadfence();
    int* leaf = bar + (blockIdx.x & (NLEAF - 1)) * LSTR;
    int* root = bar + NLEAF * LSTR;
    int* flag = bar + NLEAF * LSTR + LSTR;
    int v = __hip_atomic_fetch_add(leaf, 1, __ATOMIC_ACQ_REL, __HIP_MEMORY_SCOPE_AGENT);
    if (v == gen * (GRID / NLEAF) - 1) {
      int w = __hip_atomic_fetch_add(root, 1, __ATOMIC_ACQ_REL, __HIP_MEMORY_SCOPE_AGENT);
      if (w == gen * NLEAF - 1)
        __hip_atomic_store(flag, gen, __ATOMIC_RELEASE, __HIP_MEMORY_SCOPE_AGENT);
    }
    while (__hip_atomic_load(flag, __ATOMIC_ACQUIRE, __HIP_MEMORY_SCOPE_AGENT) < gen)
      __builtin_amdgcn_s_sleep(2);
    __threadfence();
  }
  __syncthreads();
}

// Prep: zero out + pack + barrier block, compute simplex values from img,
// build sort keys, structural edge->triangle adjacency (race-free by halves).
__global__ __launch_bounds__(256) void k_prep(
    const float* img, const int* edges, const int* tri_edges,
    float* vals, u64* keys, uint32_t* pack, int* adj, int* bar, float* out,
    int N, int E, int F, int m, int out_n, int barN) {
  int i = blockIdx.x * blockDim.x + threadIdx.x;
  int FH = F >> 1;
  if (i < barN) bar[i] = 0;
  if (i < out_n) out[i] = 0.0f;
  if (i < m) {
    pack[i] = 0u;
    float v;
    if (i < N) {
      v = img[i];
    } else if (i < N + E) {
      int e = i - N;
      v = fmaxf(img[edges[2 * e]], img[edges[2 * e + 1]]);
    } else {
      int t = i - N - E;
      float mx = -3.402823466e38f;
      #pragma unroll
      for (int k = 0; k < 3; ++k) {
        int e = tri_edges[3 * t + k];
        mx = fmaxf(mx, fmaxf(img[edges[2 * e]], img[edges[2 * e + 1]]));
      }
      v = mx;
    }
    vals[i] = v;
    keys[i] = ((u64)f2ord(v) << 32) | (u64)(uint32_t)i;
  }
  if (i < 3 * F) {
    // t < F/2 (A-half) and t >= F/2 (B-half): every edge touches at most one
    // triangle of each half -> plain stores, no atomics.
    int e = tri_edges[i];
    int t = i / 3;
    adj[2 * e + (t >= FH ? 1 : 0)] = t;
  }
}

__global__ __launch_bounds__(BLK) void k_solve(
    const int* edges, const u64* keys, uint32_t* pack, const int* adj,
    int* vr_to_rank, int* er_to_rank, int* noderank1,
    uint32_t* eAB0, uint32_t* eAB1, float* vals, float* vsorted,
    int* bar, float* out, int N, int E, int F, int m, int W, int C) {
  __shared__ __align__(16) int s_par[2 * (FMAXC + 1)];
  __shared__ uint32_t s_rc[64];
  __shared__ int s_ci[64];
  __shared__ int2 s_pairs[64];
  __shared__ int s_cnt[2];
  int tid = threadIdx.x, bid = blockIdx.x;

  // ---- Phase 1: counting-rank (1024-key tiles; one cell per block) ----
  {
    u64* s_tile = (u64*)s_par;  // aliased; used only in this phase
    int NTt = (m + TSZ - 1) / TSZ;
    int KBt = (m + BLK - 1) / BLK;
    int ncell = NTt * KBt;
    for (int cell = bid; cell < ncell; cell += GRID) {
      int tIdx = cell % NTt, kb = cell / NTt;
      int base = tIdx * TSZ;
      int lim = min(TSZ, m - base);
      __syncthreads();
      s_tile[tid] = (tid < lim) ? keys[base + tid] : ~0ull;
      __syncthreads();
      int ki = kb * BLK + tid;
      u64 k0 = (ki < m) ? keys[ki] : ~0ull;
      int cls0 = (ki < N) ? 0 : (ki < N + E ? 1 : 2);
      int sb1 = min(max(N - base, 0), lim);
      int sb2 = min(max(N + E - base, 0), lim);
      int segb[4] = {0, sb1, sb2, lim};
      int tot = 0, cc = 0;
      #pragma unroll
      for (int sg = 0; sg < 3; ++sg) {
        int lo = segb[sg], hh = segb[sg + 1], t = 0, j = lo;
        if (j < hh && (j & 1)) { t += (s_tile[j] < k0); ++j; }
        #pragma unroll 4
        for (; j + 1 < hh; j += 2) {
          t += (s_tile[j] < k0) + (s_tile[j + 1] < k0);
        }
        if (j < hh) t += (s_tile[j] < k0);
        tot += t;
        if (cls0 == sg) cc += t;
      }
      if (ki < m) atomicAdd(&pack[ki], ((uint32_t)cc << 16) | (uint32_t)tot);
    }
  }
  gbar(bar, 1);

  // ---- Phase 2: maps (scatter + relabeled edge lists, geometric boundary) ----
  for (int i = bid * BLK + tid; i < m; i += GRID * BLK) {
    uint32_t pk = pack[i];
    int rank = (int)(pk & 0xffffu);
    int cls = (int)(pk >> 16);
    vsorted[rank] = vals[i];
    if (i < N) {
      vr_to_rank[cls] = rank;
    } else if (i < N + E) {
      int e = i - N, er = cls;
      er_to_rank[er] = rank;
      int a = edges[2 * e], b = edges[2 * e + 1];
      uint32_t va = pack[a] >> 16, vb = pack[b] >> 16;
      eAB0[er] = (va << 16) | vb;
      int ra = a / W, ca = a - ra * W, rb = b / W, cb = b - rb * W;
      bool he = (ra == rb), ve = (ca == cb);
      bool v0 = !((he && ra == W - 1) || (ve && ca == W - 1));  // A-half present?
      bool v1 = !((he && ra == 0) || (ve && ca == 0));          // B-half present?
      uint32_t na = v0 ? ((uint32_t)F - (pack[N + E + adj[2 * e]] >> 16)) : 0u;
      uint32_t nb = v1 ? ((uint32_t)F - (pack[N + E + adj[2 * e + 1]] >> 16)) : 0u;
      eAB1[E - 1 - er] = (na << 16) | nb;
    } else {
      noderank1[F - cls] = rank;  // dual node id = F - trank (outer = 0)
    }
  }
  gbar(bar, 2);

  // ---- Phase 3: range-parallel elder-rule pairing, split-serial, emit ----
  {
    int g = bid >> 7;          // 0 = primal/dim0, 1 = dual-reversed/dim1
    int r = bid & (KRANGES - 1);
    int NODES = (g == 0) ? N : (F + 1);
    const uint32_t* eAB = (g == 0) ? eAB0 : eAB1;
    int P = r * C;
    if (P < E) {
      int hi = min(P + C, E);
      int nR = hi - P;
      int n1 = (nR + 1) >> 1;
      int n2 = nR - n1;
      int Q = P + n1;
      int* par1 = s_par;
      int* par2 = s_par + (FMAXC + 1);
      volatile int* vp1 = par1;
      volatile int* vp2 = par2;
      for (int x = tid; x < NODES; x += BLK) par1[x] = x;
      __syncthreads();
      // hook prefix [0, P) into par1
      for (int i = tid; i < P; i += BLK) hook(vp1, eAB[i]);
      __syncthreads();
      // compress par1
      for (int x = tid; x < NODES; x += BLK) {
        int r0 = x;
        while (vp1[r0] != r0) r0 = vp1[r0];
        par1[x] = r0;
      }
      __syncthreads();
      // par2 = par1; then hook R1 = [P, Q) into par2
      for (int x = tid; x < NODES; x += BLK) par2[x] = par1[x];
      __syncthreads();
      for (int i = tid; i < n1; i += BLK) hook(vp2, eAB[P + i]);
      __syncthreads();
      // compress par2
      for (int x = tid; x < NODES; x += BLK) {
        int r0 = x;
        while (vp2[r0] != r0) r0 = vp2[r0];
        par2[x] = r0;
      }
      __syncthreads();
      // pre-resolve candidate roots: R1 via par1, R2 via par2
      for (int q = tid; q < nR; q += BLK) {
        int sub = (q >= n1);
        int qq = sub ? q - n1 : q;
        uint32_t ab = eAB[(sub ? Q : P) + qq];
        const int* par = sub ? par2 : par1;
        int ra = par[ab >> 16], rb = par[ab & 0xffffu];
        s_rc[sub * 32 + qq] = ((uint32_t)ra << 16) | (uint32_t)rb;
      }
      __syncthreads();
      // wave 0: R1 on par1; wave 1: R2 on par2 (concurrent serial UFs)
      if (tid < 128) {
        int sub = tid >> 6;
        int lane = tid & 63;
        int nC = sub ? n2 : n1;
        int ebase = sub ? Q : P;
        uint32_t* rc = s_rc + sub * 32;
        int* ci = s_ci + sub * 32;
        int* par = sub ? par2 : par1;
        uint32_t rr = (lane < nC) ? rc[lane] : 0u;
        int keep = (lane < nC) && ((rr >> 16) != (rr & 0xffffu));
        u64 mask = __ballot(keep);
        if (keep) {
          int idx = __popcll(mask & ((1ull << lane) - 1ull));
          rc[idx] = rr;
          ci[idx] = lane;
        }
        int kc = __popcll(mask);
        if (lane == 0) {
          int c = 0;
          for (int i = 0; i < kc; ++i) {
            uint32_t rr2 = rc[i];
            int x = (int)(rr2 >> 16), y = (int)(rr2 & 0xffffu);
            while (par[x] != x) { par[x] = par[par[x]]; x = par[x]; }
            while (par[y] != y) { par[y] = par[par[y]]; y = par[y]; }
            if (x != y) {
              int die = x > y ? x : y, sur = x < y ? x : y;
              par[die] = sur;
              s_pairs[sub * 32 + c] = make_int2(die, ebase + ci[i]);
              c++;
            }
          }
          s_cnt[sub] = c;
        }
      }
      __syncthreads();
      // emit
      int c0 = s_cnt[0], c1 = s_cnt[1];
      if (g == 0) {
        for (int q = tid; q < c0 + c1; q += BLK) {
          int2 pq = s_pairs[q < c0 ? q : 32 + (q - c0)];
          int b = vr_to_rank[pq.x], d = er_to_rank[pq.y];
          out[2 * b] = vsorted[b];
          out[2 * b + 1] = vsorted[d];
        }
        if (r == 0 && tid == 0) {
          // essential dim-0 class: rank 0 birth, death = fmax (rank m-1)
          out[0] = vsorted[0];
          out[1] = vsorted[m - 1];
        }
      } else {
        float* o1 = out + 2 * (size_t)m;
        for (int q = tid; q < c0 + c1; q += BLK) {
          int2 pq = s_pairs[q < c0 ? q : 32 + (q - c0)];
          int er = E - 1 - pq.y;
          int b = er_to_rank[er], d = noderank1[pq.x];
          o1[2 * b] = vsorted[b];
          o1[2 * b + 1] = vsorted[d];
        }
      }
    }
  }
}

extern "C" void kernel_launch(void* const* d_in, const int* in_sizes, int n_in,
                              void* d_out, int out_size, void* d_ws, size_t ws_size,
                              hipStream_t stream) {
  const float* img = (const float*)d_in[0];
  const int* edges = (const int*)d_in[1];
  const int* tri_edges = (const int*)d_in[2];
  int N = in_sizes[0];
  int E = in_sizes[1] / 2;
  int F = in_sizes[2] / 3;
  int m = N + E + F;
  int C = (E + KRANGES - 1) / KRANGES;
  int W = (int)(sqrt((double)N) + 0.5);
  int barN = NLEAF * LSTR + 2 * LSTR;
  float* out = (float*)d_out;

  char* p = (char*)d_ws;
  auto alloc = [&](size_t bytes) { char* r = p; p += (bytes + 255) & ~(size_t)255; return r; };
  int* bar         = (int*)alloc((size_t)barN * 4);
  u64* keys        = (u64*)alloc((size_t)m * 8);
  float* vals      = (float*)alloc((size_t)m * 4);
  float* vsorted   = (float*)alloc((size_t)m * 4);
  uint32_t* pack   = (uint32_t*)alloc((size_t)m * 4);
  int* vr_to_rank  = (int*)alloc((size_t)N * 4);
  int* er_to_rank  = (int*)alloc((size_t)E * 4);
  int* noderank1   = (int*)alloc((size_t)(F + 1) * 4);
  int* adj         = (int*)alloc((size_t)E * 8);
  uint32_t* eAB0   = (uint32_t*)alloc((size_t)E * 4);
  uint32_t* eAB1   = (uint32_t*)alloc((size_t)E * 4);
  (void)ws_size; (void)n_in;

  int out_n = out_size;
  int PM = out_n > m ? out_n : m;
  if (PM < 3 * F) PM = 3 * F;
  if (PM < barN) PM = barN;

  k_prep<<<(PM + 255) / 256, 256, 0, stream>>>(img, edges, tri_edges, vals, keys,
                                               pack, adj, bar, out, N, E, F, m,
                                               out_n, barN);
  k_solve<<<GRID, BLK, 0, stream>>>(edges, keys, pack, adj,
                                    vr_to_rank, er_to_rank, noderank1,
                                    eAB0, eAB1, vals, vsorted,
                                    bar, out, N, E, F, m, W, C);
}

// Round 10
// 70.441 us; speedup vs baseline: 2.2723x; 2.0974x over previous
//
#include <hip/hip_runtime.h>
#include <stdint.h>
#include <math.h>

typedef unsigned long long u64;

// Problem-size caps (H=W=48 grid per reference).
#define FMAXC 4418
#define KRANGES 128
#define BLK 1024
#define TSZ 1024

// Monotone float -> uint32 mapping (IEEE total order for non-NaN).
static __device__ __forceinline__ uint32_t f2ord(float f) {
  uint32_t u = __float_as_uint(f);
  return (u & 0x80000000u) ? ~u : (u | 0x80000000u);
}

// Closed-form edge endpoints for the reference grid complex.
// he: e in [0,nh): r=e/(W-1), c=e%(W-1): (r,c)-(r,c+1)
// ve: e-nh in [0,nv): r=q/W, c=q%W: (r,c)-(r+1,c)
// de: q=e-nh-nv: r=q/(W-1), c=q%(W-1): (r,c+1)-(r+1,c)
static __device__ __forceinline__ void edge_ab(int e, int W, int nh, int nv,
                                               int* a, int* b) {
  if (e < nh) {
    int r = e / (W - 1), c = e - r * (W - 1);
    *a = r * W + c; *b = *a + 1;
  } else if (e < nh + nv) {
    int q = e - nh;
    int r = q / W, c = q - r * W;
    *a = r * W + c; *b = *a + W;
  } else {
    int q = e - nh - nv;
    int r = q / (W - 1), c = q - r * (W - 1);
    *a = r * W + c + 1; *b = (r + 1) * W + c;
  }
}

// Closed-form edge -> adjacent triangles (ids, -1 = none/outer).
// triA(r,c) = r*(W-1)+c ; triB(r,c) = FH + r*(W-1)+c, FH=(H-1)(W-1).
static __device__ __forceinline__ void edge_tri(int e, int W, int H, int nh, int nv,
                                                int FH, int* tA, int* tB) {
  if (e < nh) {
    int r = e / (W - 1), c = e - r * (W - 1);
    *tA = (r <= H - 2) ? r * (W - 1) + c : -1;
    *tB = (r >= 1) ? FH + (r - 1) * (W - 1) + c : -1;
  } else if (e < nh + nv) {
    int q = e - nh;
    int r = q / W, c = q - r * W;
    *tA = (c <= W - 2) ? r * (W - 1) + c : -1;
    *tB = (c >= 1) ? FH + r * (W - 1) + (c - 1) : -1;
  } else {
    int q = e - nh - nv;
    int r = q / (W - 1), c = q - r * (W - 1);
    *tA = r * (W - 1) + c;
    *tB = FH + r * (W - 1) + c;
  }
}

// ECL-CC representative with inline path compression.
static __device__ __forceinline__ int rep(volatile int* par, int v) {
  int p = par[v];
  if (p == v) return v;
  int gp = par[p];
  while (p != gp) {
    par[v] = gp;
    v = p; p = gp; gp = par[p];
  }
  return p;
}

// Async min-hook of one edge into a DSU (dual-chain walks + CAS).
static __device__ __forceinline__ void hook(volatile int* vp, uint32_t ab) {
  int va = (int)(ab >> 16), vb = (int)(ab & 0xffffu);
  int pa = vp[va], pb = vp[vb];
  int ga = vp[pa], gb = vp[pb];
  while (pa != ga || pb != gb) {
    if (pa != ga) { vp[va] = ga; va = pa; pa = ga; ga = vp[pa]; }
    if (pb != gb) { vp[vb] = gb; vb = pb; pb = gb; gb = vp[pb]; }
  }
  int u = pa, w = pb;
  while (u != w) {
    if (u < w) { int t = u; u = w; w = t; }
    int old = atomicCAS((int*)&vp[u], u, w);
    if (old == u) break;
    u = rep(vp, old);
    w = rep(vp, w);
  }
}

// Prep: zero out + pack, compute simplex values (closed-form vertex sets) and
// sort keys. No adjacency staging (closed-form later), no atomics.
__global__ __launch_bounds__(256) void k_prep(
    const float* img, float* vals, u64* keys, uint32_t* pack, float* out,
    int N, int E, int F, int m, int W, int H, int nh, int nv, int FH, int out_n) {
  int i = blockIdx.x * blockDim.x + threadIdx.x;
  if (i < out_n) out[i] = 0.0f;
  if (i >= m) return;
  pack[i] = 0u;
  float v;
  if (i < N) {
    v = img[i];
  } else if (i < N + E) {
    int a, b;
    edge_ab(i - N, W, nh, nv, &a, &b);
    v = fmaxf(img[a], img[b]);
  } else {
    int t = i - N - E;
    int base, o1, o2;
    if (t < FH) {
      int r = t / (W - 1), c = t - r * (W - 1);
      base = r * W + c; o1 = 1; o2 = W;          // (r,c),(r,c+1),(r+1,c)
    } else {
      int q = t - FH;
      int r = q / (W - 1), c = q - r * (W - 1);
      base = r * W + c; o1 = 1; o2 = W;          // (r,c+1),(r+1,c),(r+1,c+1)
      base += 0;                                  // handled below
      v = fmaxf(img[base + 1], fmaxf(img[base + W], img[base + W + 1]));
      vals[i] = v;
      keys[i] = ((u64)f2ord(v) << 32) | (u64)(uint32_t)i;
      return;
    }
    v = fmaxf(img[base], fmaxf(img[base + o1], img[base + o2]));
  }
  vals[i] = v;
  keys[i] = ((u64)f2ord(v) << 32) | (u64)(uint32_t)i;
}

// Counting-rank: block (tile, keyblock). Tile staged in LDS; each thread owns
// one key and counts {tile keys < key}, class-segmented by index ranges.
__global__ __launch_bounds__(BLK) void k_count(const u64* keys, uint32_t* pack,
                                               int N, int E, int m) {
  __shared__ __align__(16) u64 s_tile[TSZ];
  int tid = threadIdx.x;
  int base = blockIdx.x * TSZ;
  int lim = min(TSZ, m - base);
  s_tile[tid] = (tid < lim) ? keys[base + tid] : ~0ull;
  __syncthreads();
  int ki = blockIdx.y * BLK + tid;
  u64 k0 = (ki < m) ? keys[ki] : ~0ull;
  int cls0 = (ki < N) ? 0 : (ki < N + E ? 1 : 2);
  int sb1 = min(max(N - base, 0), lim);
  int sb2 = min(max(N + E - base, 0), lim);
  int segb[4] = {0, sb1, sb2, lim};
  int tot = 0, cc = 0;
  #pragma unroll
  for (int sg = 0; sg < 3; ++sg) {
    int lo = segb[sg], hh = segb[sg + 1], t = 0, j = lo;
    if (j < hh && (j & 1)) { t += (s_tile[j] < k0); ++j; }
    #pragma unroll 4
    for (; j + 1 < hh; j += 2) {
      t += (s_tile[j] < k0) + (s_tile[j + 1] < k0);
    }
    if (j < hh) t += (s_tile[j] < k0);
    tot += t;
    if (cls0 == sg) cc += t;
  }
  if (ki < m) atomicAdd(&pack[ki], ((uint32_t)cc << 16) | (uint32_t)tot);
}

// Maps: scatter rank data + build relabeled edge lists with closed-form dual
// adjacency. eAB0[er] = primal endpoints as vranks; eAB1[E-1-er] = dual node
// ids (node = F - trank; outer = 0; smaller = elder).
__global__ __launch_bounds__(256) void k_maps(
    const uint32_t* pack, const float* vals,
    float* vsorted, int* vr_to_rank, int* er_to_rank, int* noderank1,
    uint32_t* eAB0, uint32_t* eAB1,
    int N, int E, int F, int m, int W, int H, int nh, int nv, int FH) {
  int i = blockIdx.x * blockDim.x + threadIdx.x;
  if (i >= m) return;
  uint32_t pk = pack[i];
  int rank = (int)(pk & 0xffffu);
  int cls = (int)(pk >> 16);
  vsorted[rank] = vals[i];
  if (i < N) {
    vr_to_rank[cls] = rank;
  } else if (i < N + E) {
    int e = i - N, er = cls;
    er_to_rank[er] = rank;
    int a, b;
    edge_ab(e, W, nh, nv, &a, &b);
    uint32_t va = pack[a] >> 16, vb = pack[b] >> 16;
    eAB0[er] = (va << 16) | vb;
    int tA, tB;
    edge_tri(e, W, H, nh, nv, FH, &tA, &tB);
    uint32_t na = (tA >= 0) ? ((uint32_t)F - (pack[N + E + tA] >> 16)) : 0u;
    uint32_t nb = (tB >= 0) ? ((uint32_t)F - (pack[N + E + tB] >> 16)) : 0u;
    eAB1[E - 1 - er] = (na << 16) | nb;
  } else {
    noderank1[F - cls] = rank;  // dual node id = F - trank (outer = 0)
  }
}

// Range-parallel elder-rule pairing + emit. Block (g, r): graph g (0 = primal
// /dim0, 1 = dual-reversed/dim1), range [P, P+C). Prefix DSU via async hooking
// + compression; range split in half (R1 serial on par1, R2 serial on par2 =
// par1 + R1 hooks) so the two serial UFs run concurrently on waves 0/1.
__global__ __launch_bounds__(BLK) void k_pair(
    const uint32_t* eAB0, const uint32_t* eAB1,
    const int* vr_to_rank, const int* er_to_rank, const int* noderank1,
    const float* vsorted, float* out, int N, int E, int F, int C, int m) {
  __shared__ __align__(16) int s_par[2 * (FMAXC + 1)];
  __shared__ uint32_t s_rc[64];
  __shared__ int s_ci[64];
  __shared__ int2 s_pairs[64];
  __shared__ int s_cnt[2];
  int tid = threadIdx.x, bid = blockIdx.x;
  int g = bid >> 7;
  int r = bid & (KRANGES - 1);
  int NODES = (g == 0) ? N : (F + 1);
  const uint32_t* eAB = (g == 0) ? eAB0 : eAB1;
  int P = r * C;
  if (P >= E) return;
  int hi = min(P + C, E);
  int nR = hi - P;
  int n1 = (nR + 1) >> 1;
  int n2 = nR - n1;
  int Q = P + n1;
  int* par1 = s_par;
  int* par2 = s_par + (FMAXC + 1);
  volatile int* vp1 = par1;
  volatile int* vp2 = par2;
  for (int x = tid; x < NODES; x += BLK) par1[x] = x;
  __syncthreads();
  for (int i = tid; i < P; i += BLK) hook(vp1, eAB[i]);
  __syncthreads();
  for (int x = tid; x < NODES; x += BLK) {
    int r0 = x;
    while (vp1[r0] != r0) r0 = vp1[r0];
    par1[x] = r0;
  }
  __syncthreads();
  for (int x = tid; x < NODES; x += BLK) par2[x] = par1[x];
  __syncthreads();
  for (int i = tid; i < n1; i += BLK) hook(vp2, eAB[P + i]);
  __syncthreads();
  for (int x = tid; x < NODES; x += BLK) {
    int r0 = x;
    while (vp2[r0] != r0) r0 = vp2[r0];
    par2[x] = r0;
  }
  __syncthreads();
  for (int q = tid; q < nR; q += BLK) {
    int sub = (q >= n1);
    int qq = sub ? q - n1 : q;
    uint32_t ab = eAB[(sub ? Q : P) + qq];
    const int* par = sub ? par2 : par1;
    int ra = par[ab >> 16], rb = par[ab & 0xffffu];
    s_rc[sub * 32 + qq] = ((uint32_t)ra << 16) | (uint32_t)rb;
  }
  __syncthreads();
  if (tid < 128) {
    int sub = tid >> 6;
    int lane = tid & 63;
    int nC = sub ? n2 : n1;
    int ebase = sub ? Q : P;
    uint32_t* rc = s_rc + sub * 32;
    int* ci = s_ci + sub * 32;
    int* par = sub ? par2 : par1;
    uint32_t rr = (lane < nC) ? rc[lane] : 0u;
    int keep = (lane < nC) && ((rr >> 16) != (rr & 0xffffu));
    u64 mask = __ballot(keep);
    if (keep) {
      int idx = __popcll(mask & ((1ull << lane) - 1ull));
      rc[idx] = rr;
      ci[idx] = lane;
    }
    int kc = __popcll(mask);
    if (lane == 0) {
      int c = 0;
      for (int i = 0; i < kc; ++i) {
        uint32_t rr2 = rc[i];
        int x = (int)(rr2 >> 16), y = (int)(rr2 & 0xffffu);
        while (par[x] != x) { par[x] = par[par[x]]; x = par[x]; }
        while (par[y] != y) { par[y] = par[par[y]]; y = par[y]; }
        if (x != y) {
          int die = x > y ? x : y, sur = x < y ? x : y;
          par[die] = sur;
          s_pairs[sub * 32 + c] = make_int2(die, ebase + ci[i]);
          c++;
        }
      }
      s_cnt[sub] = c;
    }
  }
  __syncthreads();
  int c0 = s_cnt[0], c1 = s_cnt[1];
  if (g == 0) {
    for (int q = tid; q < c0 + c1; q += BLK) {
      int2 pq = s_pairs[q < c0 ? q : 32 + (q - c0)];
      int b = vr_to_rank[pq.x], d = er_to_rank[pq.y];
      out[2 * b] = vsorted[b];
      out[2 * b + 1] = vsorted[d];
    }
    if (r == 0 && tid == 0) {
      // essential dim-0 class: rank 0 birth, death = fmax (rank m-1)
      out[0] = vsorted[0];
      out[1] = vsorted[m - 1];
    }
  } else {
    float* o1 = out + 2 * (size_t)m;
    for (int q = tid; q < c0 + c1; q += BLK) {
      int2 pq = s_pairs[q < c0 ? q : 32 + (q - c0)];
      int er = E - 1 - pq.y;
      int b = er_to_rank[er], d = noderank1[pq.x];
      o1[2 * b] = vsorted[b];
      o1[2 * b + 1] = vsorted[d];
    }
  }
}

extern "C" void kernel_launch(void* const* d_in, const int* in_sizes, int n_in,
                              void* d_out, int out_size, void* d_ws, size_t ws_size,
                              hipStream_t stream) {
  const float* img = (const float*)d_in[0];
  int N = in_sizes[0];
  int E = in_sizes[1] / 2;
  int F = in_sizes[2] / 3;
  int m = N + E + F;
  int C = (E + KRANGES - 1) / KRANGES;
  int W = (int)(sqrt((double)N) + 0.5);
  int H = N / W;
  int nh = H * (W - 1);
  int nv = (H - 1) * W;
  int FH = (H - 1) * (W - 1);
  float* out = (float*)d_out;

  char* p = (char*)d_ws;
  auto alloc = [&](size_t bytes) { char* r = p; p += (bytes + 255) & ~(size_t)255; return r; };
  u64* keys        = (u64*)alloc((size_t)m * 8);
  float* vals      = (float*)alloc((size_t)m * 4);
  float* vsorted   = (float*)alloc((size_t)m * 4);
  uint32_t* pack   = (uint32_t*)alloc((size_t)m * 4);
  int* vr_to_rank  = (int*)alloc((size_t)N * 4);
  int* er_to_rank  = (int*)alloc((size_t)E * 4);
  int* noderank1   = (int*)alloc((size_t)(F + 1) * 4);
  uint32_t* eAB0   = (uint32_t*)alloc((size_t)E * 4);
  uint32_t* eAB1   = (uint32_t*)alloc((size_t)E * 4);
  (void)ws_size; (void)n_in;

  int out_n = out_size;
  int PM = out_n > m ? out_n : m;
  int NTt = (m + TSZ - 1) / TSZ;
  int KBt = (m + BLK - 1) / BLK;

  k_prep<<<(PM + 255) / 256, 256, 0, stream>>>(img, vals, keys, pack, out,
                                               N, E, F, m, W, H, nh, nv, FH, out_n);
  dim3 cg(NTt, KBt);
  k_count<<<cg, BLK, 0, stream>>>(keys, pack, N, E, m);
  k_maps<<<(m + 255) / 256, 256, 0, stream>>>(pack, vals, vsorted,
                                              vr_to_rank, er_to_rank, noderank1,
                                              eAB0, eAB1, N, E, F, m, W, H, nh, nv, FH);
  k_pair<<<2 * KRANGES, BLK, 0, stream>>>(eAB0, eAB1, vr_to_rank, er_to_rank,
                                          noderank1, vsorted, out, N, E, F, C, m);
}

// Round 12
// 60.373 us; speedup vs baseline: 2.6512x; 1.1668x over previous
//
#include <hip/hip_runtime.h>
#include <stdint.h>
#include <math.h>

typedef unsigned long long u64;

// Problem-size caps (H=W=48 grid per reference).
#define FMAXC 4418
#define KRANGES 128
#define BLK 1024
#define TSZ 1024

// Monotone float -> uint32 mapping (IEEE total order for non-NaN).
static __device__ __forceinline__ uint32_t f2ord(float f) {
  uint32_t u = __float_as_uint(f);
  return (u & 0x80000000u) ? ~u : (u | 0x80000000u);
}

// Closed-form edge endpoints for the reference grid complex.
static __device__ __forceinline__ void edge_ab(int e, int W, int nh, int nv,
                                               int* a, int* b) {
  if (e < nh) {
    int r = e / (W - 1), c = e - r * (W - 1);
    *a = r * W + c; *b = *a + 1;
  } else if (e < nh + nv) {
    int q = e - nh;
    int r = q / W, c = q - r * W;
    *a = r * W + c; *b = *a + W;
  } else {
    int q = e - nh - nv;
    int r = q / (W - 1), c = q - r * (W - 1);
    *a = r * W + c + 1; *b = (r + 1) * W + c;
  }
}

// Closed-form edge -> adjacent triangles (ids, -1 = none/outer).
static __device__ __forceinline__ void edge_tri(int e, int W, int H, int nh, int nv,
                                                int FH, int* tA, int* tB) {
  if (e < nh) {
    int r = e / (W - 1), c = e - r * (W - 1);
    *tA = (r <= H - 2) ? r * (W - 1) + c : -1;
    *tB = (r >= 1) ? FH + (r - 1) * (W - 1) + c : -1;
  } else if (e < nh + nv) {
    int q = e - nh;
    int r = q / W, c = q - r * W;
    *tA = (c <= W - 2) ? r * (W - 1) + c : -1;
    *tB = (c >= 1) ? FH + r * (W - 1) + (c - 1) : -1;
  } else {
    int q = e - nh - nv;
    int r = q / (W - 1), c = q - r * (W - 1);
    *tA = r * (W - 1) + c;
    *tB = FH + r * (W - 1) + c;
  }
}

// ECL-CC representative with inline path compression.
static __device__ __forceinline__ int rep(volatile int* par, int v) {
  int p = par[v];
  if (p == v) return v;
  int gp = par[p];
  while (p != gp) {
    par[v] = gp;
    v = p; p = gp; gp = par[p];
  }
  return p;
}

// Async min-hook of one edge into a DSU (dual-chain walks + CAS).
static __device__ __forceinline__ void hook(volatile int* vp, uint32_t ab) {
  int va = (int)(ab >> 16), vb = (int)(ab & 0xffffu);
  int pa = vp[va], pb = vp[vb];
  int ga = vp[pa], gb = vp[pb];
  while (pa != ga || pb != gb) {
    if (pa != ga) { vp[va] = ga; va = pa; pa = ga; ga = vp[pa]; }
    if (pb != gb) { vp[vb] = gb; vb = pb; pb = gb; gb = vp[pb]; }
  }
  int u = pa, w = pb;
  while (u != w) {
    if (u < w) { int t = u; u = w; w = t; }
    int old = atomicCAS((int*)&vp[u], u, w);
    if (old == u) break;
    u = rep(vp, old);
    w = rep(vp, w);
  }
}

// Prep: zero out + pack, compute simplex values (closed-form vertex sets) and
// sort keys.
__global__ __launch_bounds__(256) void k_prep(
    const float* img, float* vals, u64* keys, uint32_t* pack, float* out,
    int N, int E, int F, int m, int W, int H, int nh, int nv, int FH, int out_n) {
  int i = blockIdx.x * blockDim.x + threadIdx.x;
  if (i < out_n) out[i] = 0.0f;
  if (i >= m) return;
  pack[i] = 0u;
  float v;
  if (i < N) {
    v = img[i];
  } else if (i < N + E) {
    int a, b;
    edge_ab(i - N, W, nh, nv, &a, &b);
    v = fmaxf(img[a], img[b]);
  } else {
    int t = i - N - E;
    if (t < FH) {
      int r = t / (W - 1), c = t - r * (W - 1);
      int base = r * W + c;
      v = fmaxf(img[base], fmaxf(img[base + 1], img[base + W]));
    } else {
      int q = t - FH;
      int r = q / (W - 1), c = q - r * (W - 1);
      int base = r * W + c;
      v = fmaxf(img[base + 1], fmaxf(img[base + W], img[base + W + 1]));
    }
  }
  vals[i] = v;
  keys[i] = ((u64)f2ord(v) << 32) | (u64)(uint32_t)i;
}

// Counting-rank via per-tile segment sort + binary search.
// Block (tile, keyblock): stage the tile's 3 class segments into padded LDS
// chunks, bitonic-sort all 3 chunks concurrently (chunk-local network), then
// each thread's key does 3 lower-bound searches -> per-class + total counts.
__global__ __launch_bounds__(BLK) void k_count(const u64* keys, uint32_t* pack,
                                               int N, int E, int m) {
  __shared__ __align__(16) u64 s[3 * TSZ];
  int tid = threadIdx.x;
  int base = blockIdx.x * TSZ;
  int lim = min(TSZ, m - base);
  int sb1 = min(max(N - base, 0), lim);
  int sb2 = min(max(N + E - base, 0), lim);
  // init padding, then scatter tile elements into their class chunk
  s[tid] = ~0ull; s[TSZ + tid] = ~0ull; s[2 * TSZ + tid] = ~0ull;
  __syncthreads();
  if (tid < lim) {
    u64 kv = keys[base + tid];
    int seg = (tid < sb1) ? 0 : (tid < sb2 ? 1 : 2);
    int pos = (tid < sb1) ? tid : (tid < sb2 ? tid - sb1 : tid - sb2);
    s[seg * TSZ + pos] = kv;
  }
  // bitonic sort of the 3 chunks concurrently (local index network)
  for (int k = 2; k <= TSZ; k <<= 1) {
    for (int j = k >> 1; j > 0; j >>= 1) {
      __syncthreads();
      int lj = tid ^ j;
      if (lj > tid) {
        bool up = ((tid & k) == 0);
        #pragma unroll
        for (int c = 0; c < 3; ++c) {
          u64 a = s[c * TSZ + tid], b = s[c * TSZ + lj];
          if (up ? (a > b) : (a < b)) {
            s[c * TSZ + tid] = b;
            s[c * TSZ + lj] = a;
          }
        }
      }
    }
  }
  __syncthreads();
  // per-key: 3 lower-bound searches (count of elements < key per class chunk).
  // The step-walk reaches at most TSZ-1; final probe fixes the all-below case.
  int ki = blockIdx.y * BLK + tid;
  if (ki >= m) return;
  u64 k0 = keys[ki];
  int cls0 = (ki < N) ? 0 : (ki < N + E ? 1 : 2);
  int cnt[3];
  #pragma unroll
  for (int c = 0; c < 3; ++c) {
    const u64* sc = s + c * TSZ;
    int lo = 0;
    #pragma unroll
    for (int step = TSZ >> 1; step >= 1; step >>= 1) {
      if (sc[lo + step - 1] < k0) lo += step;
    }
    lo += (sc[lo] < k0) ? 1 : 0;   // off-by-one fix: count==TSZ case
    cnt[c] = lo;
  }
  uint32_t tot = (uint32_t)(cnt[0] + cnt[1] + cnt[2]);
  uint32_t cc = (uint32_t)cnt[cls0];
  atomicAdd(&pack[ki], (cc << 16) | tot);
}

// Maps: scatter rank data + build relabeled edge lists with closed-form dual
// adjacency. eAB0[er] = primal endpoints as vranks; eAB1[E-1-er] = dual node
// ids (node = F - trank; outer = 0; smaller = elder).
__global__ __launch_bounds__(256) void k_maps(
    const uint32_t* pack, const float* vals,
    float* vsorted, int* vr_to_rank, int* er_to_rank, int* noderank1,
    uint32_t* eAB0, uint32_t* eAB1,
    int N, int E, int F, int m, int W, int H, int nh, int nv, int FH) {
  int i = blockIdx.x * blockDim.x + threadIdx.x;
  if (i >= m) return;
  uint32_t pk = pack[i];
  int rank = (int)(pk & 0xffffu);
  int cls = (int)(pk >> 16);
  vsorted[rank] = vals[i];
  if (i < N) {
    vr_to_rank[cls] = rank;
  } else if (i < N + E) {
    int e = i - N, er = cls;
    er_to_rank[er] = rank;
    int a, b;
    edge_ab(e, W, nh, nv, &a, &b);
    uint32_t va = pack[a] >> 16, vb = pack[b] >> 16;
    eAB0[er] = (va << 16) | vb;
    int tA, tB;
    edge_tri(e, W, H, nh, nv, FH, &tA, &tB);
    uint32_t na = (tA >= 0) ? ((uint32_t)F - (pack[N + E + tA] >> 16)) : 0u;
    uint32_t nb = (tB >= 0) ? ((uint32_t)F - (pack[N + E + tB] >> 16)) : 0u;
    eAB1[E - 1 - er] = (na << 16) | nb;
  } else {
    noderank1[F - cls] = rank;  // dual node id = F - trank (outer = 0)
  }
}

// Range-parallel elder-rule pairing + emit (proven round-9/10 logic).
__global__ __launch_bounds__(BLK) void k_pair(
    const uint32_t* eAB0, const uint32_t* eAB1,
    const int* vr_to_rank, const int* er_to_rank, const int* noderank1,
    const float* vsorted, float* out, int N, int E, int F, int C, int m) {
  __shared__ __align__(16) int s_par[2 * (FMAXC + 1)];
  __shared__ uint32_t s_rc[64];
  __shared__ int s_ci[64];
  __shared__ int2 s_pairs[64];
  __shared__ int s_cnt[2];
  int tid = threadIdx.x, bid = blockIdx.x;
  int g = bid >> 7;
  int r = bid & (KRANGES - 1);
  int NODES = (g == 0) ? N : (F + 1);
  const uint32_t* eAB = (g == 0) ? eAB0 : eAB1;
  int P = r * C;
  if (P >= E) return;
  int hi = min(P + C, E);
  int nR = hi - P;
  int n1 = (nR + 1) >> 1;
  int n2 = nR - n1;
  int Q = P + n1;
  int* par1 = s_par;
  int* par2 = s_par + (FMAXC + 1);
  volatile int* vp1 = par1;
  volatile int* vp2 = par2;
  for (int x = tid; x < NODES; x += BLK) par1[x] = x;
  __syncthreads();
  for (int i = tid; i < P; i += BLK) hook(vp1, eAB[i]);
  __syncthreads();
  for (int x = tid; x < NODES; x += BLK) {
    int r0 = x;
    while (vp1[r0] != r0) r0 = vp1[r0];
    par1[x] = r0;
  }
  __syncthreads();
  for (int x = tid; x < NODES; x += BLK) par2[x] = par1[x];
  __syncthreads();
  for (int i = tid; i < n1; i += BLK) hook(vp2, eAB[P + i]);
  __syncthreads();
  for (int x = tid; x < NODES; x += BLK) {
    int r0 = x;
    while (vp2[r0] != r0) r0 = vp2[r0];
    par2[x] = r0;
  }
  __syncthreads();
  for (int q = tid; q < nR; q += BLK) {
    int sub = (q >= n1);
    int qq = sub ? q - n1 : q;
    uint32_t ab = eAB[(sub ? Q : P) + qq];
    const int* par = sub ? par2 : par1;
    int ra = par[ab >> 16], rb = par[ab & 0xffffu];
    s_rc[sub * 32 + qq] = ((uint32_t)ra << 16) | (uint32_t)rb;
  }
  __syncthreads();
  if (tid < 128) {
    int sub = tid >> 6;
    int lane = tid & 63;
    int nC = sub ? n2 : n1;
    int ebase = sub ? Q : P;
    uint32_t* rc = s_rc + sub * 32;
    int* ci = s_ci + sub * 32;
    int* par = sub ? par2 : par1;
    uint32_t rr = (lane < nC) ? rc[lane] : 0u;
    int keep = (lane < nC) && ((rr >> 16) != (rr & 0xffffu));
    u64 mask = __ballot(keep);
    if (keep) {
      int idx = __popcll(mask & ((1ull << lane) - 1ull));
      rc[idx] = rr;
      ci[idx] = lane;
    }
    int kc = __popcll(mask);
    if (lane == 0) {
      int c = 0;
      for (int i = 0; i < kc; ++i) {
        uint32_t rr2 = rc[i];
        int x = (int)(rr2 >> 16), y = (int)(rr2 & 0xffffu);
        while (par[x] != x) { par[x] = par[par[x]]; x = par[x]; }
        while (par[y] != y) { par[y] = par[par[y]]; y = par[y]; }
        if (x != y) {
          int die = x > y ? x : y, sur = x < y ? x : y;
          par[die] = sur;
          s_pairs[sub * 32 + c] = make_int2(die, ebase + ci[i]);
          c++;
        }
      }
      s_cnt[sub] = c;
    }
  }
  __syncthreads();
  int c0 = s_cnt[0], c1 = s_cnt[1];
  if (g == 0) {
    for (int q = tid; q < c0 + c1; q += BLK) {
      int2 pq = s_pairs[q < c0 ? q : 32 + (q - c0)];
      int b = vr_to_rank[pq.x], d = er_to_rank[pq.y];
      out[2 * b] = vsorted[b];
      out[2 * b + 1] = vsorted[d];
    }
    if (r == 0 && tid == 0) {
      // essential dim-0 class: rank 0 birth, death = fmax (rank m-1)
      out[0] = vsorted[0];
      out[1] = vsorted[m - 1];
    }
  } else {
    float* o1 = out + 2 * (size_t)m;
    for (int q = tid; q < c0 + c1; q += BLK) {
      int2 pq = s_pairs[q < c0 ? q : 32 + (q - c0)];
      int er = E - 1 - pq.y;
      int b = er_to_rank[er], d = noderank1[pq.x];
      o1[2 * b] = vsorted[b];
      o1[2 * b + 1] = vsorted[d];
    }
  }
}

extern "C" void kernel_launch(void* const* d_in, const int* in_sizes, int n_in,
                              void* d_out, int out_size, void* d_ws, size_t ws_size,
                              hipStream_t stream) {
  const float* img = (const float*)d_in[0];
  int N = in_sizes[0];
  int E = in_sizes[1] / 2;
  int F = in_sizes[2] / 3;
  int m = N + E + F;
  int C = (E + KRANGES - 1) / KRANGES;
  int W = (int)(sqrt((double)N) + 0.5);
  int H = N / W;
  int nh = H * (W - 1);
  int nv = (H - 1) * W;
  int FH = (H - 1) * (W - 1);
  float* out = (float*)d_out;

  char* p = (char*)d_ws;
  auto alloc = [&](size_t bytes) { char* r = p; p += (bytes + 255) & ~(size_t)255; return r; };
  u64* keys        = (u64*)alloc((size_t)m * 8);
  float* vals      = (float*)alloc((size_t)m * 4);
  float* vsorted   = (float*)alloc((size_t)m * 4);
  uint32_t* pack   = (uint32_t*)alloc((size_t)m * 4);
  int* vr_to_rank  = (int*)alloc((size_t)N * 4);
  int* er_to_rank  = (int*)alloc((size_t)E * 4);
  int* noderank1   = (int*)alloc((size_t)(F + 1) * 4);
  uint32_t* eAB0   = (uint32_t*)alloc((size_t)E * 4);
  uint32_t* eAB1   = (uint32_t*)alloc((size_t)E * 4);
  (void)ws_size; (void)n_in;

  int out_n = out_size;
  int PM = out_n > m ? out_n : m;
  int NTt = (m + TSZ - 1) / TSZ;
  int KBt = (m + BLK - 1) / BLK;

  k_prep<<<(PM + 255) / 256, 256, 0, stream>>>(img, vals, keys, pack, out,
                                               N, E, F, m, W, H, nh, nv, FH, out_n);
  dim3 cg(NTt, KBt);
  k_count<<<cg, BLK, 0, stream>>>(keys, pack, N, E, m);
  k_maps<<<(m + 255) / 256, 256, 0, stream>>>(pack, vals, vsorted,
                                              vr_to_rank, er_to_rank, noderank1,
                                              eAB0, eAB1, N, E, F, m, W, H, nh, nv, FH);
  k_pair<<<2 * KRANGES, BLK, 0, stream>>>(eAB0, eAB1, vr_to_rank, er_to_rank,
                                          noderank1, vsorted, out, N, E, F, C, m);
}